// Round 11
// baseline (83.523 us; speedup 1.0000x reference)
//
#include <hip/hip_runtime.h>

#define B_ 4
#define C_ 16
#define H_ 64
#define W_ 64
#define F_ 32
#define S_ 66                   // padded row stride
#define CH_ (S_ * S_)           // padded channel = 4356 floats
#define NPAD_ (B_ * C_ * CH_)   // 1.12 MB in d_ws
#define CST 12                  // LDS floats per (c,tap): n0..n5,d0..d3,pad2

// Prolog: physical zero-pad of x into d_ws as (B,C,66,66).
__global__ __launch_bounds__(256)
void pad_kernel(const float* __restrict__ x, float* __restrict__ xp) {
    const int i  = blockIdx.x * 256 + threadIdx.x;
    const int cc = i % S_;
    const int t  = i / S_;
    const int r  = t % S_;
    const int bc = t / S_;
    float v = 0.f;
    if (r >= 1 && r <= H_ && cc >= 1 && cc <= W_)
        v = x[(size_t)bc * (H_ * W_) + (r - 1) * W_ + (cc - 1)];
    xp[i] = v;
}

// 4 px/thread (vertical quad) x 4 ch/thread (4-way channel split).
// Block 256 = 64 cols x 4 channel-groups; covers 4 rows x 64 cols of one (b,f).
// 2048 blocks -> 8192 waves -> 8/SIMD.
// R10 post-mortem: 2px shape was LDS-pipe bound (32 waves x 27 ds_read/ch =
// 69k cyc/CU > 41k VALU). 4px halves DS cost per eval -> LDS 34.5k < VALU,
// back to VALU-bound with full occupancy.
__global__ __launch_bounds__(256)
void ka_rconv_kernel(const float* __restrict__ xp,
                     const float* __restrict__ nums,
                     const float* __restrict__ denoms,
                     float* __restrict__ out) {
    __shared__ alignas(16) float sc[C_ * 9 * CST];   // 6.9 KB coeffs for this f
    __shared__ float red[3 * 4 * 64];                // 3 partial groups x 4 rows x 64 cols

    const int tid = threadIdx.x;
    const int col = tid & 63;          // lane = column -> coalesced
    const int wg  = tid >> 6;          // channel group 0..3 (wave-uniform)

    int bid = blockIdx.x;
    const int f  = bid & 31;  bid >>= 5;
    const int t4 = bid & 15;  bid >>= 4;
    const int b  = bid;
    const int gy0 = t4 * 4;            // this block's 4 output rows

    // ---- stage this f's coefficients into LDS (coalesced, once per block) ----
    {
        const float* np = nums + (size_t)f * (C_ * 54);
        for (int i = tid; i < C_ * 54; i += 256) {
            int e = i / 6, j = i - e * 6;
            sc[e * CST + j] = np[i];
        }
        const float* dp = denoms + (size_t)f * (C_ * 36);
        for (int i = tid; i < C_ * 36; i += 256) {
            int e = i / 4, j = i - e * 4;
            sc[e * CST + 6 + j] = dp[i];
        }
    }
    __syncthreads();

    const int chb = __builtin_amdgcn_readfirstlane(wg * 4);
    // padded base: input row gy0-1 -> padded row gy0; input col col-1 -> padded col col
    const float* xb = xp + ((size_t)(b * C_ + chb)) * CH_ + gy0 * S_ + col;
    const float* cp = sc + chb * (9 * CST);

    float acc[4] = {0.f, 0.f, 0.f, 0.f};

    for (int c = 0; c < 4; ++c) {
        const float* xr = xb + c * CH_;
        float3 rv[6];                      // padded rows gy0..gy0+5, cols col..col+2
        #pragma unroll
        for (int k = 0; k < 6; ++k)
            rv[k] = *(const float3*)(xr + k * S_);   // global_load_dwordx3

        const float* ce = cp + c * (9 * CST);
        #pragma unroll
        for (int t = 0; t < 9; ++t) {
            const float4 k0 = *(const float4*)(ce + t * CST);      // n0 n1 n2 n3
            const float4 k1 = *(const float4*)(ce + t * CST + 4);  // n4 n5 d0 d1
            const float2 k2 = *(const float2*)(ce + t * CST + 8);  // d2 d3
            const int a = t / 3, j = t % 3;
            #pragma unroll
            for (int p = 0; p < 4; ++p) {
                const float3 r3 = rv[p + a];
                const float xv = (j == 0) ? r3.x : (j == 1) ? r3.y : r3.z;

                float P = fmaf(k1.y, xv, k1.x);
                P = fmaf(P, xv, k0.w);
                P = fmaf(P, xv, k0.z);
                P = fmaf(P, xv, k0.y);
                P = fmaf(P, xv, k0.x);

                float Q = fmaf(k2.y, xv, k2.x);
                Q = fmaf(Q, xv, k1.w);
                Q = fmaf(Q, xv, k1.z);
                Q *= xv;
                Q = 1.0f + fabsf(Q);

                acc[p] = fmaf(P, __builtin_amdgcn_rcpf(Q), acc[p]);
            }
        }
    }

    // 4-way channel reduction through LDS (wave-uniform branches).
    if (wg > 0) {
        #pragma unroll
        for (int p = 0; p < 4; ++p)
            red[((wg - 1) * 4 + p) * 64 + col] = acc[p];
    }
    __syncthreads();
    if (wg == 0) {
        float* op = out + (((size_t)b * F_ + f) * H_ + gy0) * W_ + col;
        #pragma unroll
        for (int p = 0; p < 4; ++p) {
            float s = acc[p] + red[(0 * 4 + p) * 64 + col]
                             + red[(1 * 4 + p) * 64 + col]
                             + red[(2 * 4 + p) * 64 + col];
            op[p * W_] = s;
        }
    }
}

extern "C" void kernel_launch(void* const* d_in, const int* in_sizes, int n_in,
                              void* d_out, int out_size, void* d_ws, size_t ws_size,
                              hipStream_t stream) {
    const float* x      = (const float*)d_in[0];
    const float* nums   = (const float*)d_in[1];
    const float* denoms = (const float*)d_in[2];
    float* outp = (float*)d_out;
    float* xpad = (float*)d_ws;

    pad_kernel<<<NPAD_ / 256, 256, 0, stream>>>(x, xpad);
    dim3 grid(B_ * 16 * F_);   // 2048 blocks: (b, 4-row tile, f)
    ka_rconv_kernel<<<grid, 256, 0, stream>>>(xpad, nums, denoms, outp);
}